// Round 7
// baseline (148.717 us; speedup 1.0000x reference)
//
#include <hip/hip_runtime.h>
#include <hip/hip_bf16.h>
#include <math.h>

#define NN 256
#define CC 128
#define HH 4
#define DD 32

typedef uint4 u128;
typedef __bf16 bf16x8 __attribute__((ext_vector_type(8)));
typedef float f32x4 __attribute__((ext_vector_type(4)));

#define LOG2E 1.4426950408889634f
#define QSC (0.17677669529663687f * LOG2E)   // 1/sqrt(32) * log2(e), folded into q

// ---------------------------------------------------------------------------
// K0 prep: bias2 = PERMUTED bias layout so attn's per-lane bias loads are
//          fully coalesced (see attn kernel comment).
//          Wt_qkv[n][k] = bf16(Wqkv[k][n]); Wt_out[n][k] = bf16(Wout[k][n])
// ---------------------------------------------------------------------------
__global__ __launch_bounds__(256) void prep_kernel(
    const float* __restrict__ dm, const int* __restrict__ mask,
    const float* __restrict__ dscale,
    const float* __restrict__ Wqkv, const float* __restrict__ Wout,
    float* __restrict__ bias2,
    __hip_bfloat16* __restrict__ Wt_qkv, __hip_bfloat16* __restrict__ Wt_out)
{
    const int b = blockIdx.x, t = threadIdx.x;
    if (b < 256) {
        const int j = b, k = t;               // coalesced source read
        int idx = j * 256 + k;
        float v = mask[idx] ? -INFINITY : dscale[0] * dm[idx] * LOG2E;
        int c = k >> 5, bb = (k >> 4) & 1, quad = (k >> 2) & 3, r = k & 3;
        int dst = ((((c * 2 + bb) * 16 + (j >> 4)) * 64) + quad * 16 + (j & 15)) * 4 + r;
        bias2[dst] = v;
    } else if (b < 448) {
        int idx = (b - 256) * 256 + t;         // [0, 49152)
        int n = idx >> 7, k = idx & 127;
        Wt_qkv[idx] = __float2bfloat16(Wqkv[(size_t)k * 384 + n]);
    } else {
        int idx = (b - 448) * 256 + t;         // [0, 16384)
        int n = idx >> 7, k = idx & 127;
        Wt_out[idx] = __float2bfloat16(Wout[(size_t)k * CC + n]);
    }
}

// ---------------------------------------------------------------------------
// K2: FUSED qkv + attention. One block per (i, h); grid bi = h*256 + i so the
//   4 h-blocks of each i share bi%8 -> same XCD -> L2-dedup of pair rows.
//   Phase 3 (in-block qkv): each wave computes K/V/Q for ITS OWN 32 j-rows:
//     pf = pair[i] rows (fp32 global -> bf16 regs, no LDS staging),
//     wf = Wt_qkv head-slice rows (L1/L2-hot, 12 KB unique per block),
//     acc = mfma(pf, wf): lane(quad,n16) holds T[j=quad*4+reg][d=n16-block]
//     -> scattered u16 stores build Ks[j][d], VTs[d][perm(j)], Qs[j][d]
//     with bqkv added (and QSC folded into Q) — numerics identical to the
//     old standalone qkv kernel.
//   Phase 4: unchanged S^T attention (coalesced bias2 in MFMA C-operand,
//   exp2 packs straight into PV B-frag via the V k-permutation).
//   LDS 56.5 KB -> 2 blocks/CU. Eliminates 48 MB qkv write + 48 MB read.
// ---------------------------------------------------------------------------
__global__ __launch_bounds__(512, 4) void attn_fused_kernel(
    const float* __restrict__ pair,           // [65536,128] fp32
    const __hip_bfloat16* __restrict__ Wt,    // [384,128] bf16 (transposed Wqkv)
    const float* __restrict__ bqkv,           // [384]
    const float* __restrict__ bias2,          // [256,256] permuted, *log2e
    __hip_bfloat16* __restrict__ attn_out)    // [65536,128]
{
    __shared__ __align__(16) __hip_bfloat16 Ks[NN][40];      // 20.0 KB
    __shared__ __align__(16) __hip_bfloat16 VTs[DD][264];    // 16.5 KB
    __shared__ __align__(16) __hip_bfloat16 Qs[NN][40];      // 20.0 KB

    const int bi = blockIdx.x;
    const int i = bi & 255, h = bi >> 8;
    const int t = threadIdx.x;
    const int w = t >> 6, lane = t & 63;
    const int n16 = lane & 15, quad = lane >> 4;

    // ---- phase 3a: pair rows (wave-own) fp32 -> bf16 pf fragments --------
    bf16x8 pf[2][4];
    #pragma unroll
    for (int jt2 = 0; jt2 < 2; ++jt2) {
        const float* prow = pair + ((size_t)i * NN + w * 32 + jt2 * 16 + n16) * CC;
        float4 x[4], y[4];
        #pragma unroll
        for (int ks = 0; ks < 4; ++ks) {
            x[ks] = *(const float4*)(prow + ks * 32 + quad * 8);
            y[ks] = *(const float4*)(prow + ks * 32 + quad * 8 + 4);
        }
        #pragma unroll
        for (int ks = 0; ks < 4; ++ks) {
            __hip_bfloat162 a01 = __float22bfloat162_rn(float2{x[ks].x, x[ks].y});
            __hip_bfloat162 a23 = __float22bfloat162_rn(float2{x[ks].z, x[ks].w});
            __hip_bfloat162 a45 = __float22bfloat162_rn(float2{y[ks].x, y[ks].y});
            __hip_bfloat162 a67 = __float22bfloat162_rn(float2{y[ks].z, y[ks].w});
            u128 pk;
            pk.x = *(unsigned int*)&a01;
            pk.y = *(unsigned int*)&a23;
            pk.z = *(unsigned int*)&a45;
            pk.w = *(unsigned int*)&a67;
            pf[jt2][ks] = *(bf16x8*)&pk;
        }
    }

    // ---- phase 3b: K, V, Q = pair @ W-slice + b (per-tensor) -------------
    #pragma unroll
    for (int tt = 0; tt < 3; ++tt) {
        const int tb = (tt == 0) ? 128 : (tt == 1) ? 256 : 0;   // k, v, q
        bf16x8 wf[2][4];
        #pragma unroll
        for (int db = 0; db < 2; ++db)
            #pragma unroll
            for (int ks = 0; ks < 4; ++ks)
                wf[db][ks] = *(const bf16x8*)(Wt + (size_t)(tb + h * 32 + db * 16 + n16) * CC + ks * 32 + quad * 8);
        float b0 = bqkv[tb + h * 32 + n16];
        float b1 = bqkv[tb + h * 32 + 16 + n16];

        f32x4 acc[2][2];
        #pragma unroll
        for (int jt2 = 0; jt2 < 2; ++jt2)
            #pragma unroll
            for (int db = 0; db < 2; ++db) acc[jt2][db] = (f32x4){0.f, 0.f, 0.f, 0.f};
        #pragma unroll
        for (int ks = 0; ks < 4; ++ks)
            #pragma unroll
            for (int jt2 = 0; jt2 < 2; ++jt2)
                #pragma unroll
                for (int db = 0; db < 2; ++db)
                    acc[jt2][db] = __builtin_amdgcn_mfma_f32_16x16x32_bf16(pf[jt2][ks], wf[db][ks], acc[jt2][db], 0, 0, 0);

        // lane holds T[j = w*32+jt2*16+quad*4+r][d = db*16+n16]
        #pragma unroll
        for (int jt2 = 0; jt2 < 2; ++jt2)
            #pragma unroll
            for (int db = 0; db < 2; ++db) {
                float bb = db ? b1 : b0;
                #pragma unroll
                for (int r = 0; r < 4; ++r) {
                    float v = acc[jt2][db][r] + bb;
                    int j = w * 32 + jt2 * 16 + quad * 4 + r;
                    int d = db * 16 + n16;
                    if (tt == 0) {
                        Ks[j][d] = __float2bfloat16(v);
                    } else if (tt == 1) {
                        // k-bit perm: j=[jt2|q1q0|r1r0] -> pos=[q1q0|jt2|r1r0]
                        int pj = w * 32 + quad * 8 + jt2 * 4 + r;
                        VTs[d][pj] = __float2bfloat16(v);
                    } else {
                        Qs[j][d] = __float2bfloat16(v * QSC);
                    }
                }
            }
    }
    __syncthreads();

    // ---- phase 4: S^T attention (unchanged structure) --------------------
    #pragma unroll
    for (int jt = 0; jt < 2; ++jt) {
        const int j0 = w * 32 + jt * 16;
        const int j = j0 + n16;                // this lane's softmax column
        const int jblk = w * 2 + jt;           // j0 >> 4

        bf16x8 qa = *(const bf16x8*)&Qs[j][quad * 8];
        const float4* bb = (const float4*)bias2;

        f32x4 sm = {0.f, 0.f, 0.f, 0.f};
        f32x4 o0 = {0.f, 0.f, 0.f, 0.f}, o1 = {0.f, 0.f, 0.f, 0.f};

        #pragma unroll 2
        for (int c = 0; c < 8; ++c) {
            float4 b0 = bb[((c * 2 + 0) * 16 + jblk) * 64 + lane];
            float4 b1 = bb[((c * 2 + 1) * 16 + jblk) * 64 + lane];
            bf16x8 kb0 = *(const bf16x8*)&Ks[c * 32 + n16][quad * 8];
            bf16x8 kb1 = *(const bf16x8*)&Ks[c * 32 + 16 + n16][quad * 8];
            f32x4 s0 = __builtin_amdgcn_mfma_f32_16x16x32_bf16(
                kb0, qa, (f32x4){b0.x, b0.y, b0.z, b0.w}, 0, 0, 0);
            f32x4 s1 = __builtin_amdgcn_mfma_f32_16x16x32_bf16(
                kb1, qa, (f32x4){b1.x, b1.y, b1.z, b1.w}, 0, 0, 0);

            float p0 = __builtin_amdgcn_exp2f(s0[0]);
            float p1 = __builtin_amdgcn_exp2f(s0[1]);
            float p2 = __builtin_amdgcn_exp2f(s0[2]);
            float p3 = __builtin_amdgcn_exp2f(s0[3]);
            float p4 = __builtin_amdgcn_exp2f(s1[0]);
            float p5 = __builtin_amdgcn_exp2f(s1[1]);
            float p6 = __builtin_amdgcn_exp2f(s1[2]);
            float p7 = __builtin_amdgcn_exp2f(s1[3]);
            sm[0] += p0 + p4;
            sm[1] += p1 + p5;
            sm[2] += p2 + p6;
            sm[3] += p3 + p7;

            __hip_bfloat162 q01 = __float22bfloat162_rn(float2{p0, p1});
            __hip_bfloat162 q23 = __float22bfloat162_rn(float2{p2, p3});
            __hip_bfloat162 q45 = __float22bfloat162_rn(float2{p4, p5});
            __hip_bfloat162 q67 = __float22bfloat162_rn(float2{p6, p7});
            u128 pk;
            pk.x = *(unsigned int*)&q01;
            pk.y = *(unsigned int*)&q23;
            pk.z = *(unsigned int*)&q45;
            pk.w = *(unsigned int*)&q67;
            bf16x8 pa = *(bf16x8*)&pk;

            bf16x8 vb0 = *(const bf16x8*)&VTs[n16][c * 32 + quad * 8];
            bf16x8 vb1 = *(const bf16x8*)&VTs[16 + n16][c * 32 + quad * 8];
            o0 = __builtin_amdgcn_mfma_f32_16x16x32_bf16(vb0, pa, o0, 0, 0, 0);
            o1 = __builtin_amdgcn_mfma_f32_16x16x32_bf16(vb1, pa, o1, 0, 0, 0);
        }

        float sum = (sm[0] + sm[1]) + (sm[2] + sm[3]);
        sum += __shfl_xor(sum, 16);
        sum += __shfl_xor(sum, 32);
        float inv = 1.0f / sum;

        __hip_bfloat16* obase = attn_out + (size_t)(i * NN + j) * CC + h * DD + quad * 4;
        {
            __hip_bfloat162 h01 = __float22bfloat162_rn(float2{o0[0] * inv, o0[1] * inv});
            __hip_bfloat162 h23 = __float22bfloat162_rn(float2{o0[2] * inv, o0[3] * inv});
            uint2 pk;
            pk.x = *(unsigned int*)&h01;
            pk.y = *(unsigned int*)&h23;
            *(uint2*)(obase) = pk;
        }
        {
            __hip_bfloat162 h01 = __float22bfloat162_rn(float2{o1[0] * inv, o1[1] * inv});
            __hip_bfloat162 h23 = __float22bfloat162_rn(float2{o1[2] * inv, o1[3] * inv});
            uint2 pk;
            pk.x = *(unsigned int*)&h01;
            pk.y = *(unsigned int*)&h23;
            *(uint2*)(obase + 16) = pk;
        }
    }
}

// ---------------------------------------------------------------------------
// K3: out = attn_out @ Wout + bout  (MFMA, operand-swapped -> float4 stores)
// Staging batch-loaded: all 8 u128 loads in flight before any LDS write.
// ---------------------------------------------------------------------------
__global__ __launch_bounds__(512, 4) void out_mfma_kernel(
    const __hip_bfloat16* __restrict__ A,     // [65536,128] bf16
    const __hip_bfloat16* __restrict__ Bt,    // [128,128] bf16 (transposed W)
    const float* __restrict__ bias,           // [128]
    float* __restrict__ out)                  // [65536,128]
{
    __shared__ __align__(16) __hip_bfloat16 As[128][136];
    __shared__ __align__(16) __hip_bfloat16 Bs[128][136];
    const int t = threadIdx.x;
    const int m0 = blockIdx.x * 128;

    u128 ra[4], rb[4];
    #pragma unroll
    for (int it = 0; it < 4; ++it) {
        int idx = it * 512 + t;
        int r = idx >> 4, c8 = (idx & 15) * 8;
        ra[it] = *(const u128*)(A + (size_t)(m0 + r) * CC + c8);
    }
    #pragma unroll
    for (int it = 0; it < 4; ++it) {
        int idx = it * 512 + t;
        int n = idx >> 4, c8 = (idx & 15) * 8;
        rb[it] = *(const u128*)(Bt + (size_t)n * CC + c8);
    }
    #pragma unroll
    for (int it = 0; it < 4; ++it) {
        int idx = it * 512 + t;
        int r = idx >> 4, c8 = (idx & 15) * 8;
        *(u128*)&As[r][c8] = ra[it];
    }
    #pragma unroll
    for (int it = 0; it < 4; ++it) {
        int idx = it * 512 + t;
        int n = idx >> 4, c8 = (idx & 15) * 8;
        *(u128*)&Bs[n][c8] = rb[it];
    }
    __syncthreads();

    const int w = t >> 6, lane = t & 63;
    const int n16 = lane & 15, quad = lane >> 4;
    const int mw = (w & 3) * 32, nw = (w >> 2) * 64;

    bf16x8 pf[2][4];
    #pragma unroll
    for (int mt = 0; mt < 2; ++mt)
        #pragma unroll
        for (int ks = 0; ks < 4; ++ks)
            pf[mt][ks] = *(const bf16x8*)&As[mw + mt * 16 + n16][ks * 32 + quad * 8];

    f32x4 acc[2][4];
    #pragma unroll
    for (int mt = 0; mt < 2; ++mt)
        #pragma unroll
        for (int nt = 0; nt < 4; ++nt) acc[mt][nt] = (f32x4){0.f, 0.f, 0.f, 0.f};

    #pragma unroll
    for (int nt = 0; nt < 4; ++nt) {
        bf16x8 wf[4];
        #pragma unroll
        for (int ks = 0; ks < 4; ++ks)
            wf[ks] = *(const bf16x8*)&Bs[nw + nt * 16 + n16][ks * 32 + quad * 8];
        #pragma unroll
        for (int ks = 0; ks < 4; ++ks)
            #pragma unroll
            for (int mt = 0; mt < 2; ++mt)
                acc[mt][nt] = __builtin_amdgcn_mfma_f32_16x16x32_bf16(wf[ks], pf[mt][ks], acc[mt][nt], 0, 0, 0);
    }

    #pragma unroll
    for (int nt = 0; nt < 4; ++nt) {
        int nbase = nw + nt * 16 + quad * 4;
        float4 b4 = *(const float4*)(bias + nbase);
        #pragma unroll
        for (int mt = 0; mt < 2; ++mt) {
            int m = m0 + mw + mt * 16 + n16;
            float4 ov;
            ov.x = acc[mt][nt][0] + b4.x;
            ov.y = acc[mt][nt][1] + b4.y;
            ov.z = acc[mt][nt][2] + b4.z;
            ov.w = acc[mt][nt][3] + b4.w;
            *(float4*)&out[(size_t)m * CC + nbase] = ov;
        }
    }
}

// ---------------------------------------------------------------------------
extern "C" void kernel_launch(void* const* d_in, const int* in_sizes, int n_in,
                              void* d_out, int out_size, void* d_ws, size_t ws_size,
                              hipStream_t stream) {
    const float* pair_rep = (const float*)d_in[0];
    const float* dm       = (const float*)d_in[1];
    const float* Wqkv     = (const float*)d_in[2];
    const float* bqkv     = (const float*)d_in[3];
    const float* Wout     = (const float*)d_in[4];
    const float* bout     = (const float*)d_in[5];
    const float* dscale   = (const float*)d_in[6];
    const int*   mask     = (const int*)d_in[7];
    float* out = (float*)d_out;

    // ws: bias2[256KB] | Wt_qkv[96KB] | Wt_out[32KB] | attn[16MB]
    char* p = (char*)d_ws;
    float* bias2 = (float*)p;                 p += (size_t)NN * NN * 4;
    __hip_bfloat16* Wt_qkv = (__hip_bfloat16*)p;  p += (size_t)384 * CC * 2;
    __hip_bfloat16* Wt_out = (__hip_bfloat16*)p;  p += (size_t)CC * CC * 2;
    __hip_bfloat16* attn = (__hip_bfloat16*)p;

    prep_kernel<<<dim3(512), dim3(256), 0, stream>>>(dm, mask, dscale, Wqkv, Wout, bias2, Wt_qkv, Wt_out);
    attn_fused_kernel<<<dim3(1024), dim3(512), 0, stream>>>(pair_rep, Wt_qkv, bqkv, bias2, attn);
    out_mfma_kernel<<<dim3(512), dim3(512), 0, stream>>>(attn, Wt_out, bout, out);
}